// Round 14
// baseline (635.210 us; speedup 1.0000x reference)
//
#include <hip/hip_runtime.h>

#define NN 50000
#define NE 800000
#define EP (NE + NN)      // edges + self loops (= 850000)
#define HID 128
#define FIN 64
#define NG 64
#define SLOPE 0.2f

typedef unsigned short ushort_t;
typedef unsigned int uint_t;

__device__ __forceinline__ float wred_sum(float v) {
  for (int off = 32; off; off >>= 1) v += __shfl_xor(v, off);
  return v;
}
__device__ __forceinline__ ushort_t f2bf(float f) {   // RNE fp32 -> bf16
  uint_t b = __float_as_uint(f);
  b += 0x7fffu + ((b >> 16) & 1u);
  return (ushort_t)(b >> 16);
}

// NOTE: parameter names must not collide with .x/.y/.z/.w member tokens
#define FMA4(A_, S_, W_) \
  A_.x += (S_) * W_.x; A_.y += (S_) * W_.y; \
  A_.z += (S_) * W_.z; A_.w += (S_) * W_.w;

// ---- mean of edge weights -------------------------------------------------
__global__ void k_mean(const float* __restrict__ ew, float* __restrict__ meansum) {
  int tid = blockIdx.x * blockDim.x + threadIdx.x;
  int stride = gridDim.x * blockDim.x;
  float s = 0.f;
  for (int i = tid; i < NE; i += stride) s += ew[i];
  s = wred_sum(s);
  if ((threadIdx.x & 63) == 0) atomicAdd(meansum, s);
}

// ---- histogram of destinations (incl self loops) --------------------------
__global__ void k_hist(const int* __restrict__ edst, int* __restrict__ counts) {
  int tid = blockIdx.x * blockDim.x + threadIdx.x;
  int stride = gridDim.x * blockDim.x;
  for (int i = tid; i < EP; i += stride) {
    int d = (i < NE) ? edst[i] : (i - NE);
    atomicAdd(&counts[d], 1);
  }
}

// ---- single-block exclusive scan; also zeroes counts (reused as cursor) ---
__global__ void k_scan(int* __restrict__ counts, int* __restrict__ starts) {
  __shared__ int wsum[16];
  __shared__ int woff[16];
  int t = threadIdx.x;
  int lane = t & 63;
  int w = t >> 6;
  int carry = 0;
  for (int base = 0; base < NN; base += 1024) {
    int i = base + t;
    int v = (i < NN) ? counts[i] : 0;
    if (i < NN) counts[i] = 0;   // reset cursor for scatter
    int sc = v;
    #pragma unroll
    for (int d = 1; d < 64; d <<= 1) {
      int u = __shfl_up(sc, d);
      if (lane >= d) sc += u;
    }
    if (lane == 63) wsum[w] = sc;
    __syncthreads();
    if (w == 0 && lane < 16) {
      int x = wsum[lane];
      #pragma unroll
      for (int d = 1; d < 16; d <<= 1) {
        int u = __shfl_up(x, d);
        if (lane >= d) x += u;
      }
      woff[lane] = x;   // inclusive scan of wave sums
    }
    __syncthreads();
    int waveoff = (w == 0) ? 0 : woff[w - 1];
    if (i < NN) starts[i] = carry + waveoff + sc - v;
    carry += woff[15];
    __syncthreads();   // protect wsum/woff before next chunk
  }
  if (t == 0) starts[NN] = carry;
}

// ---- scatter edges into dst-sorted order (packed src+weight) ---------------
__global__ void k_scatter(const int* __restrict__ esrc, const int* __restrict__ edst,
                          const float* __restrict__ ew, const float* __restrict__ meansum,
                          const int* __restrict__ starts, int* __restrict__ cursor,
                          int2* __restrict__ emeta) {
  float mw = meansum[0] * (1.0f / NE);
  int tid = blockIdx.x * blockDim.x + threadIdx.x;
  int stride = gridDim.x * blockDim.x;
  for (int i = tid; i < EP; i += stride) {
    int s, d; float wv;
    if (i < NE) { s = esrc[i]; d = edst[i]; wv = ew[i]; }
    else        { s = d = i - NE; wv = mw; }
    int pos = starts[d] + atomicAdd(&cursor[d], 1);
    emeta[pos] = make_int2(s, __float_as_int(wv));
  }
}

// ---- dual fp32 GEMM: xl16 = bf16(A@Wl+bl), xr = A@Wr+br ---------------------
template <int K>
__global__ __launch_bounds__(256) void k_gemm2(const float* __restrict__ A,
                                               const float* __restrict__ Wl,
                                               const float* __restrict__ bl,
                                               const float* __restrict__ Wr,
                                               const float* __restrict__ br,
                                               ushort_t* __restrict__ xlout,
                                               float* __restrict__ xrout, int n) {
  __shared__ float As[64][K];
  int t = threadIdx.x;
  int nb = blockIdx.x * 64;
  constexpr int F4 = 16 * K;     // float4 count in the A tile
  for (int i = t; i < F4; i += 256) {
    int row = i / (K / 4);
    int c = (i % (K / 4)) * 4;
    int gn = nb + row;
    float4 v = make_float4(0.f, 0.f, 0.f, 0.f);
    if (gn < n) v = *(const float4*)(A + (size_t)gn * K + c);
    *(float4*)&As[row][c] = v;
  }
  __syncthreads();
  int fx = (t & 31) * 4;
  int ny = (t >> 5) * 8;
  float4 accL[8], accR[8];
  #pragma unroll
  for (int j = 0; j < 8; ++j) {
    accL[j] = make_float4(0.f, 0.f, 0.f, 0.f);
    accR[j] = make_float4(0.f, 0.f, 0.f, 0.f);
  }
  for (int k4 = 0; k4 < K; k4 += 4) {
    float4 wl0 = *(const float4*)(Wl + (size_t)(k4 + 0) * HID + fx);
    float4 wl1 = *(const float4*)(Wl + (size_t)(k4 + 1) * HID + fx);
    float4 wl2 = *(const float4*)(Wl + (size_t)(k4 + 2) * HID + fx);
    float4 wl3 = *(const float4*)(Wl + (size_t)(k4 + 3) * HID + fx);
    float4 wr0 = *(const float4*)(Wr + (size_t)(k4 + 0) * HID + fx);
    float4 wr1 = *(const float4*)(Wr + (size_t)(k4 + 1) * HID + fx);
    float4 wr2 = *(const float4*)(Wr + (size_t)(k4 + 2) * HID + fx);
    float4 wr3 = *(const float4*)(Wr + (size_t)(k4 + 3) * HID + fx);
    #pragma unroll
    for (int j = 0; j < 8; ++j) {
      float4 a = *(const float4*)&As[ny + j][k4];
      FMA4(accL[j], a.x, wl0); FMA4(accL[j], a.y, wl1);
      FMA4(accL[j], a.z, wl2); FMA4(accL[j], a.w, wl3);
      FMA4(accR[j], a.x, wr0); FMA4(accR[j], a.y, wr1);
      FMA4(accR[j], a.z, wr2); FMA4(accR[j], a.w, wr3);
    }
  }
  float4 bbl = *(const float4*)(bl + fx);
  float4 bbr = *(const float4*)(br + fx);
  #pragma unroll
  for (int j = 0; j < 8; ++j) {
    int gn = nb + ny + j;
    if (gn < n) {
      ushort4 u4;
      u4.x = f2bf(accL[j].x + bbl.x); u4.y = f2bf(accL[j].y + bbl.y);
      u4.z = f2bf(accL[j].z + bbl.z); u4.w = f2bf(accL[j].w + bbl.w);
      *(ushort4*)(xlout + (size_t)gn * HID + fx) = u4;
      float4 o = make_float4(accR[j].x + bbr.x, accR[j].y + bbr.y,
                             accR[j].z + bbr.z, accR[j].w + bbr.w);
      *(float4*)(xrout + (size_t)gn * HID + fx) = o;
    }
  }
}

// ---- fused GATv2 edge phase: TWO nodes per wave, interleaved chains ---------
// Straight-line code for both nodes' 16-edge batches (clamped loads + zero
// weights when a chain's range ends) -> compiler interleaves the two
// independent gather/fold chains, hiding ds_bpermute + gather latency.
// Epilogue: half 0 stores node A, half 1 stores node B.
__global__ __launch_bounds__(256, 4) void k_fused(const ushort_t* __restrict__ xl16,
                                                  const float* __restrict__ xr,
                                                  const int2* __restrict__ emeta,
                                                  const int* __restrict__ starts,
                                                  const float* __restrict__ We,
                                                  const float* __restrict__ att,
                                                  const float* __restrict__ bias,
                                                  float* __restrict__ hout) {
  int wid = blockIdx.x * (blockDim.x >> 6) + (threadIdx.x >> 6);
  int nA = wid * 2;
  if (nA >= NN) return;
  int nB = nA + 1;                       // NN even -> always valid
  int lane = threadIdx.x & 63;
  int hl = lane & 31;
  int half = lane >> 5;
  int f = hl * 4;
  float4 we  = *(const float4*)(We + f);
  float4 at  = *(const float4*)(att + f);
  float4 xroA = *(const float4*)(xr + (size_t)nA * HID + f);
  float4 xroB = *(const float4*)(xr + (size_t)nB * HID + f);
  int sA0 = starts[nA], sA1 = starts[nA + 1], sB1 = starts[nB + 1];
  // CSR contiguity: starts[nB] == sA1

  int emy = 8 * half + ((hl >> 2) & 7);
  bool b4 = (hl & 16) != 0;
  bool b3 = (hl & 8) != 0;
  bool b2 = (hl & 4) != 0;

  float ssumA = 0.f, ssumB = 0.f;
  float4 accA = make_float4(0.f, 0.f, 0.f, 0.f);
  float4 accB = make_float4(0.f, 0.f, 0.f, 0.f);

  int iA = sA0, iB = sA1;
  while (iA < sA1 || iB < sB1) {
    int baseA = iA + 8 * half;
    int baseB = iB + 8 * half;
    uint2 gA[8], gB[8];
    float pA[8], pB[8];
    #pragma unroll
    for (int k = 0; k < 8; ++k) {
      int idxA = min(baseA + k, sA1 - 1);
      int2 emA = emeta[idxA];            // uniform within half -> broadcast
      pA[k] = __int_as_float(emA.y);
      gA[k] = *(const uint2*)(xl16 + (size_t)emA.x * HID + f);
      int idxB = min(baseB + k, sB1 - 1);
      int2 emB = emeta[idxB];
      pB[k] = __int_as_float(emB.y);
      gB[k] = *(const uint2*)(xl16 + (size_t)emB.x * HID + f);
    }
    #pragma unroll
    for (int k = 0; k < 8; ++k) {
      float wkA = pA[k];
      float a0 = __uint_as_float(gA[k].x << 16)          + xroA.x + wkA * we.x;
      float a1 = __uint_as_float(gA[k].x & 0xffff0000u)  + xroA.y + wkA * we.y;
      float a2 = __uint_as_float(gA[k].y << 16)          + xroA.z + wkA * we.z;
      float a3 = __uint_as_float(gA[k].y & 0xffff0000u)  + xroA.w + wkA * we.w;
      a0 = a0 > 0.f ? a0 : SLOPE * a0;
      a1 = a1 > 0.f ? a1 : SLOPE * a1;
      a2 = a2 > 0.f ? a2 : SLOPE * a2;
      a3 = a3 > 0.f ? a3 : SLOPE * a3;
      pA[k] = a0 * at.x + a1 * at.y + a2 * at.z + a3 * at.w;
      float wkB = pB[k];
      float c0 = __uint_as_float(gB[k].x << 16)          + xroB.x + wkB * we.x;
      float c1 = __uint_as_float(gB[k].x & 0xffff0000u)  + xroB.y + wkB * we.y;
      float c2 = __uint_as_float(gB[k].y << 16)          + xroB.z + wkB * we.z;
      float c3 = __uint_as_float(gB[k].y & 0xffff0000u)  + xroB.w + wkB * we.w;
      c0 = c0 > 0.f ? c0 : SLOPE * c0;
      c1 = c1 > 0.f ? c1 : SLOPE * c1;
      c2 = c2 > 0.f ? c2 : SLOPE * c2;
      c3 = c3 > 0.f ? c3 : SLOPE * c3;
      pB[k] = c0 * at.x + c1 * at.y + c2 * at.z + c3 * at.w;
    }
    // fold-reduce both chains (independent -> interleaved by scheduler)
    float sdv, rcv;
    float qA0, qA1, qA2, qA3, qB0, qB1, qB2, qB3;
    sdv = b4 ? pA[0] : pA[4]; rcv = __shfl_xor(sdv, 16, 32); qA0 = (b4 ? pA[4] : pA[0]) + rcv;
    sdv = b4 ? pB[0] : pB[4]; rcv = __shfl_xor(sdv, 16, 32); qB0 = (b4 ? pB[4] : pB[0]) + rcv;
    sdv = b4 ? pA[1] : pA[5]; rcv = __shfl_xor(sdv, 16, 32); qA1 = (b4 ? pA[5] : pA[1]) + rcv;
    sdv = b4 ? pB[1] : pB[5]; rcv = __shfl_xor(sdv, 16, 32); qB1 = (b4 ? pB[5] : pB[1]) + rcv;
    sdv = b4 ? pA[2] : pA[6]; rcv = __shfl_xor(sdv, 16, 32); qA2 = (b4 ? pA[6] : pA[2]) + rcv;
    sdv = b4 ? pB[2] : pB[6]; rcv = __shfl_xor(sdv, 16, 32); qB2 = (b4 ? pB[6] : pB[2]) + rcv;
    sdv = b4 ? pA[3] : pA[7]; rcv = __shfl_xor(sdv, 16, 32); qA3 = (b4 ? pA[7] : pA[3]) + rcv;
    sdv = b4 ? pB[3] : pB[7]; rcv = __shfl_xor(sdv, 16, 32); qB3 = (b4 ? pB[7] : pB[3]) + rcv;
    float rA0, rA1, rB0, rB1;
    sdv = b3 ? qA0 : qA2; rcv = __shfl_xor(sdv, 8, 32); rA0 = (b3 ? qA2 : qA0) + rcv;
    sdv = b3 ? qB0 : qB2; rcv = __shfl_xor(sdv, 8, 32); rB0 = (b3 ? qB2 : qB0) + rcv;
    sdv = b3 ? qA1 : qA3; rcv = __shfl_xor(sdv, 8, 32); rA1 = (b3 ? qA3 : qA1) + rcv;
    sdv = b3 ? qB1 : qB3; rcv = __shfl_xor(sdv, 8, 32); rB1 = (b3 ? qB3 : qB1) + rcv;
    sdv = b2 ? rA0 : rA1; rcv = __shfl_xor(sdv, 4, 32);
    float lgA = (b2 ? rA1 : rA0) + rcv;
    sdv = b2 ? rB0 : rB1; rcv = __shfl_xor(sdv, 4, 32);
    float lgB = (b2 ? rB1 : rB0) + rcv;
    lgA += __shfl_xor(lgA, 1, 32);
    lgB += __shfl_xor(lgB, 1, 32);
    lgA += __shfl_xor(lgA, 2, 32);
    lgB += __shfl_xor(lgB, 2, 32);
    float wA = (iA + emy < sA1) ? __expf(lgA) : 0.f;   // also 0 once chain done
    float wB = (iB + emy < sB1) ? __expf(lgB) : 0.f;
    ssumA += wA;
    ssumB += wB;
    #pragma unroll
    for (int k = 0; k < 8; ++k) {
      float wkA = __shfl(wA, k << 2, 32);
      accA.x += wkA * __uint_as_float(gA[k].x << 16);
      accA.y += wkA * __uint_as_float(gA[k].x & 0xffff0000u);
      accA.z += wkA * __uint_as_float(gA[k].y << 16);
      accA.w += wkA * __uint_as_float(gA[k].y & 0xffff0000u);
      float wkB = __shfl(wB, k << 2, 32);
      accB.x += wkB * __uint_as_float(gB[k].x << 16);
      accB.y += wkB * __uint_as_float(gB[k].x & 0xffff0000u);
      accB.z += wkB * __uint_as_float(gB[k].y << 16);
      accB.w += wkB * __uint_as_float(gB[k].y & 0xffff0000u);
    }
    iA += 16;
    iB += 16;
  }
  // merge halves (features duplicated across halves, edges disjoint)
  accA.x += __shfl_xor(accA.x, 32);
  accA.y += __shfl_xor(accA.y, 32);
  accA.z += __shfl_xor(accA.z, 32);
  accA.w += __shfl_xor(accA.w, 32);
  accB.x += __shfl_xor(accB.x, 32);
  accB.y += __shfl_xor(accB.y, 32);
  accB.z += __shfl_xor(accB.z, 32);
  accB.w += __shfl_xor(accB.w, 32);
  float stA = wred_sum(ssumA) * 0.25f;   // each edge's w counted on 4 lanes
  float stB = wred_sum(ssumB) * 0.25f;
  float4 bb = *(const float4*)(bias + f);
  float4 oacc = half ? accB : accA;
  float oinv = 1.0f / (half ? stB : stA);
  int onode = half ? nB : nA;
  float4 o;
  o.x = fmaxf(oacc.x * oinv + bb.x, 0.f);
  o.y = fmaxf(oacc.y * oinv + bb.y, 0.f);
  o.z = fmaxf(oacc.z * oinv + bb.z, 0.f);
  o.w = fmaxf(oacc.w * oinv + bb.w, 0.f);
  *(float4*)(hout + (size_t)onode * HID + f) = o;
}

// ---- graph boundaries from sorted batch ------------------------------------
__global__ void k_bounds(const int* __restrict__ batch, int* __restrict__ gs) {
  int i = blockIdx.x * blockDim.x + threadIdx.x;
  if (i >= NN) return;
  int b = batch[i];
  if (i == 0) {
    for (int g = 0; g <= b; ++g) gs[g] = 0;
  }
  int bn = (i + 1 < NN) ? batch[i + 1] : NG;
  for (int g = b + 1; g <= bn; ++g) gs[g] = i + 1;
}

// ---- segmented mean pool + final linear (one block per graph) --------------
__global__ __launch_bounds__(256) void k_pool(const float* __restrict__ h,
                                              const int* __restrict__ gs,
                                              const float* __restrict__ Wlin,
                                              const float* __restrict__ blin,
                                              float* __restrict__ out) {
  __shared__ float red[256];
  int g = blockIdx.x;
  int t = threadIdx.x;
  int f = t & 127;
  int half = t >> 7;           // 0 or 1
  int n0 = gs[g], n1 = gs[g + 1];
  float s0 = 0.f, s1 = 0.f, s2 = 0.f, s3 = 0.f;
  int n = n0 + half;
  for (; n + 6 < n1; n += 8) {
    s0 += h[(size_t)n * HID + f];
    s1 += h[(size_t)(n + 2) * HID + f];
    s2 += h[(size_t)(n + 4) * HID + f];
    s3 += h[(size_t)(n + 6) * HID + f];
  }
  for (; n < n1; n += 2) s0 += h[(size_t)n * HID + f];
  red[t] = (s0 + s1) + (s2 + s3);
  __syncthreads();
  if (t < 128) {
    float pooled = red[t] + red[t + 128];
    float cnt = (float)max(n1 - n0, 1);
    red[t] = (pooled / cnt) * Wlin[f];
  }
  __syncthreads();
  if (t < 64) {
    float v = red[t] + red[t + 64];
    v = wred_sum(v);
    if (t == 0) out[g] = v + blin[0];
  }
}

extern "C" void kernel_launch(void* const* d_in, const int* in_sizes, int n_in,
                              void* d_out, int out_size, void* d_ws, size_t ws_size,
                              hipStream_t stream) {
  const float* x     = (const float*)d_in[0];
  const int*   ei    = (const int*)d_in[1];      // [2][NE]
  const float* ew    = (const float*)d_in[2];
  const int*   batch = (const int*)d_in[3];
  const float* W1l = (const float*)d_in[4];
  const float* b1l = (const float*)d_in[5];
  const float* W1r = (const float*)d_in[6];
  const float* b1r = (const float*)d_in[7];
  const float* We1 = (const float*)d_in[8];
  const float* at1 = (const float*)d_in[9];
  const float* bi1 = (const float*)d_in[10];
  const float* W2l = (const float*)d_in[11];
  const float* b2l = (const float*)d_in[12];
  const float* W2r = (const float*)d_in[13];
  const float* b2r = (const float*)d_in[14];
  const float* We2 = (const float*)d_in[15];
  const float* at2 = (const float*)d_in[16];
  const float* bi2 = (const float*)d_in[17];
  const float* Wlin = (const float*)d_in[18];
  const float* blin = (const float*)d_in[19];

  float* ws = (float*)d_ws;
  size_t o = 0;
  float*    xr    = ws + o; o += (size_t)NN * HID;
  float*    hb    = ws + o; o += (size_t)NN * HID;
  ushort_t* xl16  = (ushort_t*)(ws + o); o += (size_t)NN * HID / 2;
  int2*     emeta = (int2*)(ws + o); o += (size_t)2 * EP;
  int*      starts = (int*)(ws + o); o += NN + 1;
  int*      gs     = (int*)(ws + o); o += NG + 1;
  size_t zoff = o;
  int*      counts  = (int*)(ws + o); o += NN;
  float*    meansum = ws + o; o += 1;
  size_t zero_bytes = (o - zoff) * sizeof(float);

  hipMemsetAsync(counts, 0, zero_bytes, stream);

  // build dst-sorted CSR (shared by both layers) + graph bounds
  k_mean<<<256, 256, 0, stream>>>(ew, meansum);
  k_hist<<<1024, 256, 0, stream>>>(ei + NE, counts);
  k_scan<<<1, 1024, 0, stream>>>(counts, starts);
  k_scatter<<<1024, 256, 0, stream>>>(ei, ei + NE, ew, meansum, starts, counts,
                                      emeta);
  k_bounds<<<(NN + 255) / 256, 256, 0, stream>>>(batch, gs);

  int gb  = (NN + 63) / 64;                       // gemm blocks
  int nbn = NN / 8;                               // 2 nodes/wave, 4 waves/block

  // layer 1 (one dual-GEMM instead of two GEMMs)
  k_gemm2<FIN><<<gb, 256, 0, stream>>>(x, W1l, b1l, W1r, b1r, xl16, xr, NN);
  k_fused<<<nbn, 256, 0, stream>>>(xl16, xr, emeta, starts, We1, at1, bi1, hb);
  // layer 2
  k_gemm2<HID><<<gb, 256, 0, stream>>>(hb, W2l, b2l, W2r, b2r, xl16, xr, NN);
  k_fused<<<nbn, 256, 0, stream>>>(xl16, xr, emeta, starts, We2, at2, bi2, hb);
  // pool + head (no atomics: batch is sorted -> contiguous graph ranges)
  k_pool<<<NG, 256, 0, stream>>>(hb, gs, Wlin, blin, (float*)d_out);
}

// Round 15
// 405.615 us; speedup vs baseline: 1.5660x; 1.5660x over previous
//
#include <hip/hip_runtime.h>

#define NN 50000
#define NE 800000
#define EP (NE + NN)      // edges + self loops (= 850000)
#define HID 128
#define FIN 64
#define NG 64
#define SLOPE 0.2f
#define NB 49             // scan blocks: 49*1024 >= NN

typedef unsigned short ushort_t;
typedef unsigned int uint_t;

__device__ __forceinline__ float wred_sum(float v) {
  for (int off = 32; off; off >>= 1) v += __shfl_xor(v, off);
  return v;
}
__device__ __forceinline__ ushort_t f2bf(float f) {   // RNE fp32 -> bf16
  uint_t b = __float_as_uint(f);
  b += 0x7fffu + ((b >> 16) & 1u);
  return (ushort_t)(b >> 16);
}

// NOTE: parameter names must not collide with .x/.y/.z/.w member tokens
#define FMA4(A_, S_, W_) \
  A_.x += (S_) * W_.x; A_.y += (S_) * W_.y; \
  A_.z += (S_) * W_.z; A_.w += (S_) * W_.w;

// ---- histogram of real-edge destinations + mean of edge weights ------------
// Self loops are folded analytically later (deg = counts + 1).
__global__ void k_hist2(const int* __restrict__ edst, const float* __restrict__ ew,
                        int* __restrict__ counts, float* __restrict__ meansum) {
  int tid = blockIdx.x * blockDim.x + threadIdx.x;
  int stride = gridDim.x * blockDim.x;
  float s = 0.f;
  for (int i = tid; i < NE; i += stride) {
    atomicAdd(&counts[edst[i]], 1);
    s += ew[i];
  }
  s = wred_sum(s);
  if ((threadIdx.x & 63) == 0) atomicAdd(meansum, s);
}

// ---- hierarchical scan, stage 1: per-block local exclusive scan ------------
__global__ __launch_bounds__(1024) void k_scan1(const int* __restrict__ counts,
                                                int* __restrict__ starts,
                                                int* __restrict__ bsum) {
  __shared__ int wsum[16];
  __shared__ int woff[16];
  int t = threadIdx.x, lane = t & 63, w = t >> 6;
  int i = blockIdx.x * 1024 + t;
  int v = (i < NN) ? counts[i] + 1 : 0;   // +1 = self loop
  int sc = v;
  #pragma unroll
  for (int d = 1; d < 64; d <<= 1) {
    int u = __shfl_up(sc, d);
    if (lane >= d) sc += u;
  }
  if (lane == 63) wsum[w] = sc;
  __syncthreads();
  if (w == 0 && lane < 16) {
    int x = wsum[lane];
    #pragma unroll
    for (int d = 1; d < 16; d <<= 1) {
      int u = __shfl_up(x, d);
      if (lane >= d) x += u;
    }
    woff[lane] = x;
  }
  __syncthreads();
  int waveoff = (w == 0) ? 0 : woff[w - 1];
  if (i < NN) starts[i] = waveoff + sc - v;
  if (t == 1023) bsum[blockIdx.x] = woff[15];
}

// ---- scan stage 2: one wave scans the 49 block sums (exclusive) ------------
__global__ void k_scan2(int* __restrict__ bsum, int* __restrict__ starts) {
  int t = threadIdx.x;                    // 64 threads
  int v = (t < NB) ? bsum[t] : 0;
  int sc = v;
  #pragma unroll
  for (int d = 1; d < 64; d <<= 1) {
    int u = __shfl_up(sc, d);
    if (t >= d) sc += u;
  }
  if (t < NB) bsum[t] = sc - v;           // exclusive
  if (t == 0) starts[NN] = EP;
}

// ---- scan stage 3: add block offsets, zero cursor ---------------------------
__global__ __launch_bounds__(1024) void k_scan3(int* __restrict__ starts,
                                                const int* __restrict__ bsum,
                                                int* __restrict__ counts) {
  int i = blockIdx.x * 1024 + threadIdx.x;
  if (i < NN) {
    starts[i] += bsum[blockIdx.x];
    counts[i] = 0;
  }
}

// ---- scatter edges into dst-sorted order (packed src+weight) ---------------
__global__ void k_scatter(const int* __restrict__ esrc, const int* __restrict__ edst,
                          const float* __restrict__ ew, const float* __restrict__ meansum,
                          const int* __restrict__ starts, int* __restrict__ cursor,
                          int2* __restrict__ emeta) {
  float mw = meansum[0] * (1.0f / NE);
  int tid = blockIdx.x * blockDim.x + threadIdx.x;
  int stride = gridDim.x * blockDim.x;
  for (int i = tid; i < EP; i += stride) {
    int s, d; float wv;
    if (i < NE) { s = esrc[i]; d = edst[i]; wv = ew[i]; }
    else        { s = d = i - NE; wv = mw; }
    int pos = starts[d] + atomicAdd(&cursor[d], 1);
    emeta[pos] = make_int2(s, __float_as_int(wv));
  }
}

// ---- dual fp32 GEMM: xl16 = bf16(A@Wl+bl), xr = A@Wr+br ---------------------
template <int K>
__global__ __launch_bounds__(256) void k_gemm2(const float* __restrict__ A,
                                               const float* __restrict__ Wl,
                                               const float* __restrict__ bl,
                                               const float* __restrict__ Wr,
                                               const float* __restrict__ br,
                                               ushort_t* __restrict__ xlout,
                                               float* __restrict__ xrout, int n) {
  __shared__ float As[64][K];
  int t = threadIdx.x;
  int nb = blockIdx.x * 64;
  constexpr int F4 = 16 * K;     // float4 count in the A tile
  for (int i = t; i < F4; i += 256) {
    int row = i / (K / 4);
    int c = (i % (K / 4)) * 4;
    int gn = nb + row;
    float4 v = make_float4(0.f, 0.f, 0.f, 0.f);
    if (gn < n) v = *(const float4*)(A + (size_t)gn * K + c);
    *(float4*)&As[row][c] = v;
  }
  __syncthreads();
  int fx = (t & 31) * 4;
  int ny = (t >> 5) * 8;
  float4 accL[8], accR[8];
  #pragma unroll
  for (int j = 0; j < 8; ++j) {
    accL[j] = make_float4(0.f, 0.f, 0.f, 0.f);
    accR[j] = make_float4(0.f, 0.f, 0.f, 0.f);
  }
  for (int k4 = 0; k4 < K; k4 += 4) {
    float4 wl0 = *(const float4*)(Wl + (size_t)(k4 + 0) * HID + fx);
    float4 wl1 = *(const float4*)(Wl + (size_t)(k4 + 1) * HID + fx);
    float4 wl2 = *(const float4*)(Wl + (size_t)(k4 + 2) * HID + fx);
    float4 wl3 = *(const float4*)(Wl + (size_t)(k4 + 3) * HID + fx);
    float4 wr0 = *(const float4*)(Wr + (size_t)(k4 + 0) * HID + fx);
    float4 wr1 = *(const float4*)(Wr + (size_t)(k4 + 1) * HID + fx);
    float4 wr2 = *(const float4*)(Wr + (size_t)(k4 + 2) * HID + fx);
    float4 wr3 = *(const float4*)(Wr + (size_t)(k4 + 3) * HID + fx);
    #pragma unroll
    for (int j = 0; j < 8; ++j) {
      float4 a = *(const float4*)&As[ny + j][k4];
      FMA4(accL[j], a.x, wl0); FMA4(accL[j], a.y, wl1);
      FMA4(accL[j], a.z, wl2); FMA4(accL[j], a.w, wl3);
      FMA4(accR[j], a.x, wr0); FMA4(accR[j], a.y, wr1);
      FMA4(accR[j], a.z, wr2); FMA4(accR[j], a.w, wr3);
    }
  }
  float4 bbl = *(const float4*)(bl + fx);
  float4 bbr = *(const float4*)(br + fx);
  #pragma unroll
  for (int j = 0; j < 8; ++j) {
    int gn = nb + ny + j;
    if (gn < n) {
      ushort4 u4;
      u4.x = f2bf(accL[j].x + bbl.x); u4.y = f2bf(accL[j].y + bbl.y);
      u4.z = f2bf(accL[j].z + bbl.z); u4.w = f2bf(accL[j].w + bbl.w);
      *(ushort4*)(xlout + (size_t)gn * HID + fx) = u4;
      float4 o = make_float4(accR[j].x + bbr.x, accR[j].y + bbr.y,
                             accR[j].z + bbr.z, accR[j].w + bbr.w);
      *(float4*)(xrout + (size_t)gn * HID + fx) = o;
    }
  }
}

// ---- fully fused GATv2 edge phase (node per wave, half-wave float4) ---------
// Round-13 known-good version: single node per wave, packed bf16 rows,
// broadcast metadata loads, fold-reduced logits, no-max softmax.
__global__ __launch_bounds__(256, 4) void k_fused(const ushort_t* __restrict__ xl16,
                                                  const float* __restrict__ xr,
                                                  const int2* __restrict__ emeta,
                                                  const int* __restrict__ starts,
                                                  const float* __restrict__ We,
                                                  const float* __restrict__ att,
                                                  const float* __restrict__ bias,
                                                  float* __restrict__ hout) {
  int node = blockIdx.x * (blockDim.x >> 6) + (threadIdx.x >> 6);
  int lane = threadIdx.x & 63;
  if (node >= NN) return;
  int hl = lane & 31;
  int half = lane >> 5;
  int s0 = starts[node], s1 = starts[node + 1];
  int f = hl * 4;
  float4 xro = *(const float4*)(xr + (size_t)node * HID + f);
  float4 we  = *(const float4*)(We + f);
  float4 at  = *(const float4*)(att + f);

  int emy = 8 * half + ((hl >> 2) & 7);   // edge whose folded logit lands here
  bool b4 = (hl & 16) != 0;
  bool b3 = (hl & 8) != 0;
  bool b2 = (hl & 4) != 0;

  float ssum = 0.f;
  float4 acc = make_float4(0.f, 0.f, 0.f, 0.f);

  for (int i0 = s0; i0 < s1; i0 += 16) {
    int base = i0 + 8 * half;
    uint2 g[8];
    float p[8];                          // holds edge weight, then logit
    #pragma unroll
    for (int k = 0; k < 8; ++k) {
      int idx = min(base + k, s1 - 1);
      int2 em = emeta[idx];              // uniform within half -> broadcast
      p[k] = __int_as_float(em.y);
      g[k] = *(const uint2*)(xl16 + (size_t)em.x * HID + f);
    }
    #pragma unroll
    for (int k = 0; k < 8; ++k) {
      float wk = p[k];
      float t0 = __uint_as_float(g[k].x << 16)          + xro.x + wk * we.x;
      float t1 = __uint_as_float(g[k].x & 0xffff0000u)  + xro.y + wk * we.y;
      float t2 = __uint_as_float(g[k].y << 16)          + xro.z + wk * we.z;
      float t3 = __uint_as_float(g[k].y & 0xffff0000u)  + xro.w + wk * we.w;
      t0 = t0 > 0.f ? t0 : SLOPE * t0;
      t1 = t1 > 0.f ? t1 : SLOPE * t1;
      t2 = t2 > 0.f ? t2 : SLOPE * t2;
      t3 = t3 > 0.f ? t3 : SLOPE * t3;
      p[k] = t0 * at.x + t1 * at.y + t2 * at.z + t3 * at.w;
    }
    // fold-reduce: 32-lane sums of 8 logits in 9 shfls
    float sdv, rcv;
    float q0, q1, q2, q3;
    sdv = b4 ? p[0] : p[4]; rcv = __shfl_xor(sdv, 16, 32); q0 = (b4 ? p[4] : p[0]) + rcv;
    sdv = b4 ? p[1] : p[5]; rcv = __shfl_xor(sdv, 16, 32); q1 = (b4 ? p[5] : p[1]) + rcv;
    sdv = b4 ? p[2] : p[6]; rcv = __shfl_xor(sdv, 16, 32); q2 = (b4 ? p[6] : p[2]) + rcv;
    sdv = b4 ? p[3] : p[7]; rcv = __shfl_xor(sdv, 16, 32); q3 = (b4 ? p[7] : p[3]) + rcv;
    float r0, r1;
    sdv = b3 ? q0 : q2; rcv = __shfl_xor(sdv, 8, 32); r0 = (b3 ? q2 : q0) + rcv;
    sdv = b3 ? q1 : q3; rcv = __shfl_xor(sdv, 8, 32); r1 = (b3 ? q3 : q1) + rcv;
    sdv = b2 ? r0 : r1; rcv = __shfl_xor(sdv, 4, 32);
    float lg = (b2 ? r1 : r0) + rcv;
    lg += __shfl_xor(lg, 1, 32);
    lg += __shfl_xor(lg, 2, 32);
    // lg = full logit of edge (i0 + emy), replicated on 4 lanes
    float w = (i0 + emy < s1) ? __expf(lg) : 0.f;
    ssum += w;
    #pragma unroll
    for (int k = 0; k < 8; ++k) {
      float wk = __shfl(w, k << 2, 32);
      acc.x += wk * __uint_as_float(g[k].x << 16);
      acc.y += wk * __uint_as_float(g[k].x & 0xffff0000u);
      acc.z += wk * __uint_as_float(g[k].y << 16);
      acc.w += wk * __uint_as_float(g[k].y & 0xffff0000u);
    }
  }
  // merge halves (features duplicated across halves, edges disjoint)
  acc.x += __shfl_xor(acc.x, 32);
  acc.y += __shfl_xor(acc.y, 32);
  acc.z += __shfl_xor(acc.z, 32);
  acc.w += __shfl_xor(acc.w, 32);
  float st = wred_sum(ssum) * 0.25f;   // each edge's w counted on 4 lanes
  float inv = 1.0f / st;
  if (half == 0) {
    float4 bb = *(const float4*)(bias + f);
    float4 o;
    o.x = fmaxf(acc.x * inv + bb.x, 0.f);
    o.y = fmaxf(acc.y * inv + bb.y, 0.f);
    o.z = fmaxf(acc.z * inv + bb.z, 0.f);
    o.w = fmaxf(acc.w * inv + bb.w, 0.f);
    *(float4*)(hout + (size_t)node * HID + f) = o;
  }
}

// ---- graph boundaries from sorted batch ------------------------------------
__global__ void k_bounds(const int* __restrict__ batch, int* __restrict__ gs) {
  int i = blockIdx.x * blockDim.x + threadIdx.x;
  if (i >= NN) return;
  int b = batch[i];
  if (i == 0) {
    for (int g = 0; g <= b; ++g) gs[g] = 0;
  }
  int bn = (i + 1 < NN) ? batch[i + 1] : NG;
  for (int g = b + 1; g <= bn; ++g) gs[g] = i + 1;
}

// ---- segmented mean pool + final linear (one block per graph) --------------
__global__ __launch_bounds__(256) void k_pool(const float* __restrict__ h,
                                              const int* __restrict__ gs,
                                              const float* __restrict__ Wlin,
                                              const float* __restrict__ blin,
                                              float* __restrict__ out) {
  __shared__ float red[256];
  int g = blockIdx.x;
  int t = threadIdx.x;
  int f = t & 127;
  int half = t >> 7;           // 0 or 1
  int n0 = gs[g], n1 = gs[g + 1];
  float s0 = 0.f, s1 = 0.f, s2 = 0.f, s3 = 0.f;
  int n = n0 + half;
  for (; n + 6 < n1; n += 8) {
    s0 += h[(size_t)n * HID + f];
    s1 += h[(size_t)(n + 2) * HID + f];
    s2 += h[(size_t)(n + 4) * HID + f];
    s3 += h[(size_t)(n + 6) * HID + f];
  }
  for (; n < n1; n += 2) s0 += h[(size_t)n * HID + f];
  red[t] = (s0 + s1) + (s2 + s3);
  __syncthreads();
  if (t < 128) {
    float pooled = red[t] + red[t + 128];
    float cnt = (float)max(n1 - n0, 1);
    red[t] = (pooled / cnt) * Wlin[f];
  }
  __syncthreads();
  if (t < 64) {
    float v = red[t] + red[t + 64];
    v = wred_sum(v);
    if (t == 0) out[g] = v + blin[0];
  }
}

extern "C" void kernel_launch(void* const* d_in, const int* in_sizes, int n_in,
                              void* d_out, int out_size, void* d_ws, size_t ws_size,
                              hipStream_t stream) {
  const float* x     = (const float*)d_in[0];
  const int*   ei    = (const int*)d_in[1];      // [2][NE]
  const float* ew    = (const float*)d_in[2];
  const int*   batch = (const int*)d_in[3];
  const float* W1l = (const float*)d_in[4];
  const float* b1l = (const float*)d_in[5];
  const float* W1r = (const float*)d_in[6];
  const float* b1r = (const float*)d_in[7];
  const float* We1 = (const float*)d_in[8];
  const float* at1 = (const float*)d_in[9];
  const float* bi1 = (const float*)d_in[10];
  const float* W2l = (const float*)d_in[11];
  const float* b2l = (const float*)d_in[12];
  const float* W2r = (const float*)d_in[13];
  const float* b2r = (const float*)d_in[14];
  const float* We2 = (const float*)d_in[15];
  const float* at2 = (const float*)d_in[16];
  const float* bi2 = (const float*)d_in[17];
  const float* Wlin = (const float*)d_in[18];
  const float* blin = (const float*)d_in[19];

  float* ws = (float*)d_ws;
  size_t o = 0;
  float*    xr    = ws + o; o += (size_t)NN * HID;
  float*    hb    = ws + o; o += (size_t)NN * HID;
  ushort_t* xl16  = (ushort_t*)(ws + o); o += (size_t)NN * HID / 2;
  int2*     emeta = (int2*)(ws + o); o += (size_t)2 * EP;
  int*      starts = (int*)(ws + o); o += NN + 1;
  int*      gs     = (int*)(ws + o); o += NG + 1;
  int*      bsum   = (int*)(ws + o); o += NB;
  size_t zoff = o;
  int*      counts  = (int*)(ws + o); o += NN;
  float*    meansum = ws + o; o += 1;
  size_t zero_bytes = (o - zoff) * sizeof(float);

  hipMemsetAsync(counts, 0, zero_bytes, stream);

  // build dst-sorted CSR (shared by both layers) + graph bounds
  k_hist2<<<1024, 256, 0, stream>>>(ei + NE, ew, counts, meansum);
  k_scan1<<<NB, 1024, 0, stream>>>(counts, starts, bsum);
  k_scan2<<<1, 64, 0, stream>>>(bsum, starts);
  k_scan3<<<NB, 1024, 0, stream>>>(starts, bsum, counts);
  k_scatter<<<1024, 256, 0, stream>>>(ei, ei + NE, ew, meansum, starts, counts,
                                      emeta);
  k_bounds<<<(NN + 255) / 256, 256, 0, stream>>>(batch, gs);

  int gb  = (NN + 63) / 64;                       // gemm blocks
  int nbn = (NN + 3) / 4;                         // node-per-wave blocks

  // layer 1 (one dual-GEMM instead of two GEMMs)
  k_gemm2<FIN><<<gb, 256, 0, stream>>>(x, W1l, b1l, W1r, b1r, xl16, xr, NN);
  k_fused<<<nbn, 256, 0, stream>>>(xl16, xr, emeta, starts, We1, at1, bi1, hb);
  // layer 2
  k_gemm2<HID><<<gb, 256, 0, stream>>>(hb, W2l, b2l, W2r, b2r, xl16, xr, NN);
  k_fused<<<nbn, 256, 0, stream>>>(xl16, xr, emeta, starts, We2, at2, bi2, hb);
  // pool + head (no atomics: batch is sorted -> contiguous graph ranges)
  k_pool<<<NG, 256, 0, stream>>>(hb, gs, Wlin, blin, (float*)d_out);
}

// Round 16
// 394.133 us; speedup vs baseline: 1.6117x; 1.0291x over previous
//
#include <hip/hip_runtime.h>

#define NN 50000
#define NE 800000
#define EP (NE + NN)      // edges + self loops (= 850000)
#define HID 128
#define FIN 64
#define NG 64
#define SLOPE 0.2f
#define NB 49             // scan blocks: 49*1024 >= NN

typedef unsigned short ushort_t;
typedef unsigned int uint_t;
typedef __attribute__((ext_vector_type(8))) short bf16x8;
typedef __attribute__((ext_vector_type(4))) float f32x4;

__device__ __forceinline__ float wred_sum(float v) {
  for (int off = 32; off; off >>= 1) v += __shfl_xor(v, off);
  return v;
}
__device__ __forceinline__ ushort_t f2bf(float f) {   // RNE fp32 -> bf16
  uint_t b = __float_as_uint(f);
  b += 0x7fffu + ((b >> 16) & 1u);
  return (ushort_t)(b >> 16);
}
__device__ __forceinline__ float bf2f(ushort_t u) {
  return __uint_as_float((uint_t)u << 16);
}

// ---- fp32 -> bf16 convert (x feature table) --------------------------------
__global__ void k_cvt(const float* __restrict__ x, ushort_t* __restrict__ x16) {
  int i = blockIdx.x * blockDim.x + threadIdx.x;   // grid sized exactly
  float4 v = *(const float4*)(x + (size_t)i * 4);
  ushort4 u;
  u.x = f2bf(v.x); u.y = f2bf(v.y); u.z = f2bf(v.z); u.w = f2bf(v.w);
  *(ushort4*)(x16 + (size_t)i * 4) = u;
}

// ---- pack W[K x 128] fp32 into MFMA B-fragment layout WP[k/32][n][k%32] ----
__global__ void k_packW(const float* __restrict__ W, ushort_t* __restrict__ WP,
                        int K) {
  int i = blockIdx.x * blockDim.x + threadIdx.x;
  if (i >= K * HID) return;
  int k = i / HID, nn = i % HID;
  WP[((size_t)(k >> 5) * HID + nn) * 32 + (k & 31)] = f2bf(W[i]);
}

// ---- histogram of real-edge destinations + mean of edge weights ------------
__global__ void k_hist2(const int* __restrict__ edst, const float* __restrict__ ew,
                        int* __restrict__ counts, float* __restrict__ meansum) {
  int tid = blockIdx.x * blockDim.x + threadIdx.x;
  int stride = gridDim.x * blockDim.x;
  float s = 0.f;
  for (int i = tid; i < NE; i += stride) {
    atomicAdd(&counts[edst[i]], 1);
    s += ew[i];
  }
  s = wred_sum(s);
  if ((threadIdx.x & 63) == 0) atomicAdd(meansum, s);
}

// ---- hierarchical scan, stage 1: per-block local exclusive scan ------------
__global__ __launch_bounds__(1024) void k_scan1(const int* __restrict__ counts,
                                                int* __restrict__ starts,
                                                int* __restrict__ bsum) {
  __shared__ int wsum[16];
  __shared__ int woff[16];
  int t = threadIdx.x, lane = t & 63, w = t >> 6;
  int i = blockIdx.x * 1024 + t;
  int v = (i < NN) ? counts[i] + 1 : 0;   // +1 = self loop
  int sc = v;
  #pragma unroll
  for (int d = 1; d < 64; d <<= 1) {
    int u = __shfl_up(sc, d);
    if (lane >= d) sc += u;
  }
  if (lane == 63) wsum[w] = sc;
  __syncthreads();
  if (w == 0 && lane < 16) {
    int x = wsum[lane];
    #pragma unroll
    for (int d = 1; d < 16; d <<= 1) {
      int u = __shfl_up(x, d);
      if (lane >= d) x += u;
    }
    woff[lane] = x;
  }
  __syncthreads();
  int waveoff = (w == 0) ? 0 : woff[w - 1];
  if (i < NN) starts[i] = waveoff + sc - v;
  if (t == 1023) bsum[blockIdx.x] = woff[15];
}

// ---- scan stage 2: one wave scans the 49 block sums (exclusive) ------------
__global__ void k_scan2(int* __restrict__ bsum, int* __restrict__ starts) {
  int t = threadIdx.x;                    // 64 threads
  int v = (t < NB) ? bsum[t] : 0;
  int sc = v;
  #pragma unroll
  for (int d = 1; d < 64; d <<= 1) {
    int u = __shfl_up(sc, d);
    if (t >= d) sc += u;
  }
  if (t < NB) bsum[t] = sc - v;           // exclusive
  if (t == 0) starts[NN] = EP;
}

// ---- scan stage 3: add block offsets, zero cursor ---------------------------
__global__ __launch_bounds__(1024) void k_scan3(int* __restrict__ starts,
                                                const int* __restrict__ bsum,
                                                int* __restrict__ counts) {
  int i = blockIdx.x * 1024 + threadIdx.x;
  if (i < NN) {
    starts[i] += bsum[blockIdx.x];
    counts[i] = 0;
  }
}

// ---- scatter edges into dst-sorted order (packed src+weight) ---------------
__global__ void k_scatter(const int* __restrict__ esrc, const int* __restrict__ edst,
                          const float* __restrict__ ew, const float* __restrict__ meansum,
                          const int* __restrict__ starts, int* __restrict__ cursor,
                          int2* __restrict__ emeta) {
  float mw = meansum[0] * (1.0f / NE);
  int tid = blockIdx.x * blockDim.x + threadIdx.x;
  int stride = gridDim.x * blockDim.x;
  for (int i = tid; i < EP; i += stride) {
    int s, d; float wv;
    if (i < NE) { s = esrc[i]; d = edst[i]; wv = ew[i]; }
    else        { s = d = i - NE; wv = mw; }
    int pos = starts[d] + atomicAdd(&cursor[d], 1);
    emeta[pos] = make_int2(s, __float_as_int(wv));
  }
}

// ---- dual bf16 MFMA GEMM: xl16 = bf16(A@Wl+bl), xr = A@Wr+br ----------------
// 4 waves/block, wave = 16 rows x 256 cols (16 16x16 frags, K-loop of K/32).
// A-frag: lane holds A[row0 + (l&15)][kt*32 + (l>>4)*8 .. +7] (one 16B load).
// B-frag from packed WP: lane holds W[kt*32+(l>>4)*8+j][nf*16+(l&15)].
// D: col = lane&15, row = (lane>>4)*4 + reg  [verified m89 mapping].
template <int K>
__global__ __launch_bounds__(256) void k_gemmM(const ushort_t* __restrict__ A16,
                                               const ushort_t* __restrict__ WPl,
                                               const float* __restrict__ bl,
                                               const ushort_t* __restrict__ WPr,
                                               const float* __restrict__ br,
                                               ushort_t* __restrict__ xlout,
                                               float* __restrict__ xrout, int n) {
  int t = threadIdx.x;
  int wave = t >> 6, lane = t & 63;
  int m = lane & 15, kb = lane >> 4;
  int row0 = blockIdx.x * 64 + wave * 16;
  int ra = min(row0 + m, n - 1);
  f32x4 acc[16];
  #pragma unroll
  for (int i = 0; i < 16; ++i) acc[i] = (f32x4)(0.f);
  #pragma unroll
  for (int kt = 0; kt < K / 32; ++kt) {
    bf16x8 a = *(const bf16x8*)(A16 + (size_t)ra * K + kt * 32 + kb * 8);
    #pragma unroll
    for (int nf = 0; nf < 8; ++nf) {
      bf16x8 bfr = *(const bf16x8*)(WPl + ((size_t)kt * HID + nf * 16 + m) * 32 + kb * 8);
      acc[nf] = __builtin_amdgcn_mfma_f32_16x16x32_bf16(a, bfr, acc[nf], 0, 0, 0);
    }
    #pragma unroll
    for (int nf = 0; nf < 8; ++nf) {
      bf16x8 bfr = *(const bf16x8*)(WPr + ((size_t)kt * HID + nf * 16 + m) * 32 + kb * 8);
      acc[8 + nf] = __builtin_amdgcn_mfma_f32_16x16x32_bf16(a, bfr, acc[8 + nf], 0, 0, 0);
    }
  }
  #pragma unroll
  for (int nf = 0; nf < 8; ++nf) {
    int col = nf * 16 + m;
    float bbl = bl[col], bbr = br[col];
    #pragma unroll
    for (int j = 0; j < 4; ++j) {
      int r = row0 + kb * 4 + j;
      if (r < n) {
        xlout[(size_t)r * HID + col] = f2bf(acc[nf][j] + bbl);
        xrout[(size_t)r * HID + col] = acc[8 + nf][j] + bbr;
      }
    }
  }
}

// ---- fully fused GATv2 edge phase (node per wave, half-wave float4) ---------
// Round-13 structure; output now bf16 (feeds next GEMM A and pool).
__global__ __launch_bounds__(256, 4) void k_fused(const ushort_t* __restrict__ xl16,
                                                  const float* __restrict__ xr,
                                                  const int2* __restrict__ emeta,
                                                  const int* __restrict__ starts,
                                                  const float* __restrict__ We,
                                                  const float* __restrict__ att,
                                                  const float* __restrict__ bias,
                                                  ushort_t* __restrict__ hout) {
  int node = blockIdx.x * (blockDim.x >> 6) + (threadIdx.x >> 6);
  int lane = threadIdx.x & 63;
  if (node >= NN) return;
  int hl = lane & 31;
  int half = lane >> 5;
  int s0 = starts[node], s1 = starts[node + 1];
  int f = hl * 4;
  float4 xro = *(const float4*)(xr + (size_t)node * HID + f);
  float4 we  = *(const float4*)(We + f);
  float4 at  = *(const float4*)(att + f);

  int emy = 8 * half + ((hl >> 2) & 7);   // edge whose folded logit lands here
  bool b4 = (hl & 16) != 0;
  bool b3 = (hl & 8) != 0;
  bool b2 = (hl & 4) != 0;

  float ssum = 0.f;
  float4 acc = make_float4(0.f, 0.f, 0.f, 0.f);

  for (int i0 = s0; i0 < s1; i0 += 16) {
    int base = i0 + 8 * half;
    uint2 g[8];
    float p[8];                          // holds edge weight, then logit
    #pragma unroll
    for (int k = 0; k < 8; ++k) {
      int idx = min(base + k, s1 - 1);
      int2 em = emeta[idx];              // uniform within half -> broadcast
      p[k] = __int_as_float(em.y);
      g[k] = *(const uint2*)(xl16 + (size_t)em.x * HID + f);
    }
    #pragma unroll
    for (int k = 0; k < 8; ++k) {
      float wk = p[k];
      float t0 = __uint_as_float(g[k].x << 16)          + xro.x + wk * we.x;
      float t1 = __uint_as_float(g[k].x & 0xffff0000u)  + xro.y + wk * we.y;
      float t2 = __uint_as_float(g[k].y << 16)          + xro.z + wk * we.z;
      float t3 = __uint_as_float(g[k].y & 0xffff0000u)  + xro.w + wk * we.w;
      t0 = t0 > 0.f ? t0 : SLOPE * t0;
      t1 = t1 > 0.f ? t1 : SLOPE * t1;
      t2 = t2 > 0.f ? t2 : SLOPE * t2;
      t3 = t3 > 0.f ? t3 : SLOPE * t3;
      p[k] = t0 * at.x + t1 * at.y + t2 * at.z + t3 * at.w;
    }
    // fold-reduce: 32-lane sums of 8 logits in 9 shfls
    float sdv, rcv;
    float q0, q1, q2, q3;
    sdv = b4 ? p[0] : p[4]; rcv = __shfl_xor(sdv, 16, 32); q0 = (b4 ? p[4] : p[0]) + rcv;
    sdv = b4 ? p[1] : p[5]; rcv = __shfl_xor(sdv, 16, 32); q1 = (b4 ? p[5] : p[1]) + rcv;
    sdv = b4 ? p[2] : p[6]; rcv = __shfl_xor(sdv, 16, 32); q2 = (b4 ? p[6] : p[2]) + rcv;
    sdv = b4 ? p[3] : p[7]; rcv = __shfl_xor(sdv, 16, 32); q3 = (b4 ? p[7] : p[3]) + rcv;
    float r0, r1;
    sdv = b3 ? q0 : q2; rcv = __shfl_xor(sdv, 8, 32); r0 = (b3 ? q2 : q0) + rcv;
    sdv = b3 ? q1 : q3; rcv = __shfl_xor(sdv, 8, 32); r1 = (b3 ? q3 : q1) + rcv;
    sdv = b2 ? r0 : r1; rcv = __shfl_xor(sdv, 4, 32);
    float lg = (b2 ? r1 : r0) + rcv;
    lg += __shfl_xor(lg, 1, 32);
    lg += __shfl_xor(lg, 2, 32);
    // lg = full logit of edge (i0 + emy), replicated on 4 lanes
    float w = (i0 + emy < s1) ? __expf(lg) : 0.f;
    ssum += w;
    #pragma unroll
    for (int k = 0; k < 8; ++k) {
      float wk = __shfl(w, k << 2, 32);
      acc.x += wk * __uint_as_float(g[k].x << 16);
      acc.y += wk * __uint_as_float(g[k].x & 0xffff0000u);
      acc.z += wk * __uint_as_float(g[k].y << 16);
      acc.w += wk * __uint_as_float(g[k].y & 0xffff0000u);
    }
  }
  // merge halves (features duplicated across halves, edges disjoint)
  acc.x += __shfl_xor(acc.x, 32);
  acc.y += __shfl_xor(acc.y, 32);
  acc.z += __shfl_xor(acc.z, 32);
  acc.w += __shfl_xor(acc.w, 32);
  float st = wred_sum(ssum) * 0.25f;   // each edge's w counted on 4 lanes
  float inv = 1.0f / st;
  if (half == 0) {
    float4 bb = *(const float4*)(bias + f);
    ushort4 u;
    u.x = f2bf(fmaxf(acc.x * inv + bb.x, 0.f));
    u.y = f2bf(fmaxf(acc.y * inv + bb.y, 0.f));
    u.z = f2bf(fmaxf(acc.z * inv + bb.z, 0.f));
    u.w = f2bf(fmaxf(acc.w * inv + bb.w, 0.f));
    *(ushort4*)(hout + (size_t)node * HID + f) = u;
  }
}

// ---- graph boundaries from sorted batch ------------------------------------
__global__ void k_bounds(const int* __restrict__ batch, int* __restrict__ gs) {
  int i = blockIdx.x * blockDim.x + threadIdx.x;
  if (i >= NN) return;
  int b = batch[i];
  if (i == 0) {
    for (int g = 0; g <= b; ++g) gs[g] = 0;
  }
  int bn = (i + 1 < NN) ? batch[i + 1] : NG;
  for (int g = b + 1; g <= bn; ++g) gs[g] = i + 1;
}

// ---- segmented mean pool (bf16 input) + final linear ------------------------
__global__ __launch_bounds__(256) void k_pool(const ushort_t* __restrict__ h,
                                              const int* __restrict__ gs,
                                              const float* __restrict__ Wlin,
                                              const float* __restrict__ blin,
                                              float* __restrict__ out) {
  __shared__ float red[256];
  int g = blockIdx.x;
  int t = threadIdx.x;
  int f = t & 127;
  int half = t >> 7;           // 0 or 1
  int n0 = gs[g], n1 = gs[g + 1];
  float s0 = 0.f, s1 = 0.f, s2 = 0.f, s3 = 0.f;
  int n = n0 + half;
  for (; n + 6 < n1; n += 8) {
    s0 += bf2f(h[(size_t)n * HID + f]);
    s1 += bf2f(h[(size_t)(n + 2) * HID + f]);
    s2 += bf2f(h[(size_t)(n + 4) * HID + f]);
    s3 += bf2f(h[(size_t)(n + 6) * HID + f]);
  }
  for (; n < n1; n += 2) s0 += bf2f(h[(size_t)n * HID + f]);
  red[t] = (s0 + s1) + (s2 + s3);
  __syncthreads();
  if (t < 128) {
    float pooled = red[t] + red[t + 128];
    float cnt = (float)max(n1 - n0, 1);
    red[t] = (pooled / cnt) * Wlin[f];
  }
  __syncthreads();
  if (t < 64) {
    float v = red[t] + red[t + 64];
    v = wred_sum(v);
    if (t == 0) out[g] = v + blin[0];
  }
}

extern "C" void kernel_launch(void* const* d_in, const int* in_sizes, int n_in,
                              void* d_out, int out_size, void* d_ws, size_t ws_size,
                              hipStream_t stream) {
  const float* x     = (const float*)d_in[0];
  const int*   ei    = (const int*)d_in[1];      // [2][NE]
  const float* ew    = (const float*)d_in[2];
  const int*   batch = (const int*)d_in[3];
  const float* W1l = (const float*)d_in[4];
  const float* b1l = (const float*)d_in[5];
  const float* W1r = (const float*)d_in[6];
  const float* b1r = (const float*)d_in[7];
  const float* We1 = (const float*)d_in[8];
  const float* at1 = (const float*)d_in[9];
  const float* bi1 = (const float*)d_in[10];
  const float* W2l = (const float*)d_in[11];
  const float* b2l = (const float*)d_in[12];
  const float* W2r = (const float*)d_in[13];
  const float* b2r = (const float*)d_in[14];
  const float* We2 = (const float*)d_in[15];
  const float* at2 = (const float*)d_in[16];
  const float* bi2 = (const float*)d_in[17];
  const float* Wlin = (const float*)d_in[18];
  const float* blin = (const float*)d_in[19];

  float* ws = (float*)d_ws;
  size_t o = 0;
  float*    xr    = ws + o; o += (size_t)NN * HID;
  ushort_t* xl16  = (ushort_t*)(ws + o); o += (size_t)NN * HID / 2;
  ushort_t* hb16  = (ushort_t*)(ws + o); o += (size_t)NN * HID / 2;
  ushort_t* x16   = (ushort_t*)(ws + o); o += (size_t)NN * FIN / 2;
  ushort_t* WP1l  = (ushort_t*)(ws + o); o += (size_t)FIN * HID / 2;
  ushort_t* WP1r  = (ushort_t*)(ws + o); o += (size_t)FIN * HID / 2;
  ushort_t* WP2l  = (ushort_t*)(ws + o); o += (size_t)HID * HID / 2;
  ushort_t* WP2r  = (ushort_t*)(ws + o); o += (size_t)HID * HID / 2;
  int2*     emeta = (int2*)(ws + o); o += (size_t)2 * EP;
  int*      starts = (int*)(ws + o); o += NN + 1;
  int*      gs     = (int*)(ws + o); o += NG + 1;
  int*      bsum   = (int*)(ws + o); o += NB;
  size_t zoff = o;
  int*      counts  = (int*)(ws + o); o += NN;
  float*    meansum = ws + o; o += 1;
  size_t zero_bytes = (o - zoff) * sizeof(float);

  hipMemsetAsync(counts, 0, zero_bytes, stream);

  // input conversions / weight packing
  k_cvt<<<(NN * FIN / 4) / 256, 256, 0, stream>>>(x, x16);
  k_packW<<<(FIN * HID + 255) / 256, 256, 0, stream>>>(W1l, WP1l, FIN);
  k_packW<<<(FIN * HID + 255) / 256, 256, 0, stream>>>(W1r, WP1r, FIN);
  k_packW<<<(HID * HID + 255) / 256, 256, 0, stream>>>(W2l, WP2l, HID);
  k_packW<<<(HID * HID + 255) / 256, 256, 0, stream>>>(W2r, WP2r, HID);

  // build dst-sorted CSR (shared by both layers) + graph bounds
  k_hist2<<<1024, 256, 0, stream>>>(ei + NE, ew, counts, meansum);
  k_scan1<<<NB, 1024, 0, stream>>>(counts, starts, bsum);
  k_scan2<<<1, 64, 0, stream>>>(bsum, starts);
  k_scan3<<<NB, 1024, 0, stream>>>(starts, bsum, counts);
  k_scatter<<<1024, 256, 0, stream>>>(ei, ei + NE, ew, meansum, starts, counts,
                                      emeta);
  k_bounds<<<(NN + 255) / 256, 256, 0, stream>>>(batch, gs);

  int gb  = (NN + 63) / 64;                       // gemm blocks
  int nbn = (NN + 3) / 4;                         // node-per-wave blocks

  // layer 1 (MFMA dual-GEMM)
  k_gemmM<FIN><<<gb, 256, 0, stream>>>(x16, WP1l, b1l, WP1r, b1r, xl16, xr, NN);
  k_fused<<<nbn, 256, 0, stream>>>(xl16, xr, emeta, starts, We1, at1, bi1, hb16);
  // layer 2
  k_gemmM<HID><<<gb, 256, 0, stream>>>(hb16, WP2l, b2l, WP2r, b2r, xl16, xr, NN);
  k_fused<<<nbn, 256, 0, stream>>>(xl16, xr, emeta, starts, We2, at2, bi2, hb16);
  // pool + head (no atomics: batch is sorted -> contiguous graph ranges)
  k_pool<<<NG, 256, 0, stream>>>(hb16, gs, Wlin, blin, (float*)d_out);
}